// Round 1
// baseline (3418.352 us; speedup 1.0000x reference)
//
#include <hip/hip_runtime.h>

#define NN 50000
#define NE 400000
#define DD 128
#define HH 4
#define DHH 32
#define TT 3
#define RR 6
#define LL 2
#define EPSF 1e-5f

// ---------------- CSR build ----------------
__global__ void hist_kernel(const int* __restrict__ dst, int* __restrict__ cnt){
  int e = blockIdx.x*256 + threadIdx.x;
  if (e < NE) atomicAdd(&cnt[dst[e]], 1);
}

__global__ void scan_kernel(const int* __restrict__ deg, int* __restrict__ rowptr){
  __shared__ int wsum[16];
  __shared__ int carrySh;
  int tid = threadIdx.x, lane = tid & 63, w = tid >> 6;
  if (tid == 0){ carrySh = 0; rowptr[0] = 0; }
  __syncthreads();
  for (int base = 0; base < NN; base += 1024){
    int i = base + tid;
    int v = (i < NN) ? deg[i] : 0;
    int s = v;
    #pragma unroll
    for (int off=1; off<64; off<<=1){ int t = __shfl_up(s, off); if (lane >= off) s += t; }
    if (lane == 63) wsum[w] = s;
    __syncthreads();
    if (w == 0 && lane < 16){
      int t = wsum[lane];
      #pragma unroll
      for (int off=1; off<16; off<<=1){ int u = __shfl_up(t, off); if (lane >= off) t += u; }
      wsum[lane] = t;
    }
    __syncthreads();
    int waveOff = (w == 0) ? 0 : wsum[w-1];
    int incl = s + waveOff + carrySh;
    if (i < NN) rowptr[i+1] = incl;
    __syncthreads();
    if (tid == 0) carrySh += wsum[15];
    __syncthreads();
  }
}

__global__ void scatter_kernel(const int* __restrict__ dst, const int* __restrict__ rowptr,
                               int* __restrict__ cnt, int* __restrict__ csr){
  int e = blockIdx.x*256 + threadIdx.x;
  if (e < NE){
    int d = dst[e];
    int pos = rowptr[d] + atomicAdd(&cnt[d], 1);
    csr[pos] = e;
  }
}

// transpose W_msg[l][h][r][d][o] -> WT[l][h][r][o][d]  (both layers at once)
__global__ void wt_kernel(const float* __restrict__ W, float* __restrict__ WT){
  int i = blockIdx.x*256 + threadIdx.x;
  if (i < LL*HH*RR*DHH*DHH){
    int o = i & 31, d = (i >> 5) & 31, hr = i >> 10;
    WT[(hr << 10) + o*DHH + d] = W[i];
  }
}

// ---------------- typed K/Q/V GEMM ----------------
__global__ __launch_bounds__(256) void kqv_kernel(
    const float* __restrict__ x, const int* __restrict__ ntype,
    const float* __restrict__ Wk, const float* __restrict__ Wq, const float* __restrict__ Wv,
    float* __restrict__ kout, float* __restrict__ qout, float* __restrict__ vout)
{
  __shared__ float xs[16][DD];
  __shared__ int nts[16];
  int tid = threadIdx.x;
  int n0 = blockIdx.x * 16;
  #pragma unroll
  for (int it=0; it<8; it++){
    int i = tid + it*256;
    xs[i>>7][i&127] = x[(size_t)n0*DD + i];
  }
  if (tid < 16) nts[tid] = ntype[n0 + tid];
  __syncthreads();
  int c = tid & 127, nb = (tid >> 7) * 8;
  float ak[8], aq[8], av[8];
  #pragma unroll
  for (int j=0;j<8;j++){ ak[j]=0.f; aq[j]=0.f; av[j]=0.f; }
  int t0 = nts[nb];
  bool uni = true;
  #pragma unroll
  for (int j=1;j<8;j++) uni = uni && (nts[nb+j] == t0);
  if (uni){
    const float* wk = Wk + (size_t)t0*DD*DD + c;
    const float* wq = Wq + (size_t)t0*DD*DD + c;
    const float* wv = Wv + (size_t)t0*DD*DD + c;
    for (int d=0; d<DD; d+=4){
      float k0=wk[(d+0)*DD], k1=wk[(d+1)*DD], k2=wk[(d+2)*DD], k3=wk[(d+3)*DD];
      float q0=wq[(d+0)*DD], q1=wq[(d+1)*DD], q2=wq[(d+2)*DD], q3=wq[(d+3)*DD];
      float v0=wv[(d+0)*DD], v1=wv[(d+1)*DD], v2=wv[(d+2)*DD], v3=wv[(d+3)*DD];
      #pragma unroll
      for (int j=0;j<8;j++){
        float4 xv = *(const float4*)&xs[nb+j][d];
        ak[j] += xv.x*k0 + xv.y*k1 + xv.z*k2 + xv.w*k3;
        aq[j] += xv.x*q0 + xv.y*q1 + xv.z*q2 + xv.w*q3;
        av[j] += xv.x*v0 + xv.y*v1 + xv.z*v2 + xv.w*v3;
      }
    }
  } else {
    #pragma unroll
    for (int j=0;j<8;j++){
      int t = nts[nb+j];
      const float* wk = Wk + (size_t)t*DD*DD + c;
      const float* wq = Wq + (size_t)t*DD*DD + c;
      const float* wv = Wv + (size_t)t*DD*DD + c;
      float sk=0.f, sq=0.f, sv=0.f;
      for (int d=0; d<DD; d+=4){
        float4 xv = *(const float4*)&xs[nb+j][d];
        sk += xv.x*wk[d*DD] + xv.y*wk[(d+1)*DD] + xv.z*wk[(d+2)*DD] + xv.w*wk[(d+3)*DD];
        sq += xv.x*wq[d*DD] + xv.y*wq[(d+1)*DD] + xv.z*wq[(d+2)*DD] + xv.w*wq[(d+3)*DD];
        sv += xv.x*wv[d*DD] + xv.y*wv[(d+1)*DD] + xv.z*wv[(d+2)*DD] + xv.w*wv[(d+3)*DD];
      }
      ak[j]=sk; aq[j]=sq; av[j]=sv;
    }
  }
  #pragma unroll
  for (int j=0;j<8;j++){
    size_t row = (size_t)(n0 + nb + j)*DD + c;
    kout[row]=ak[j]; qout[row]=aq[j]; vout[row]=av[j];
  }
}

// ---------------- edge attention logits ----------------
__global__ __launch_bounds__(256) void logits_kernel(
    const float* __restrict__ kbuf, const float* __restrict__ qbuf,
    const int* __restrict__ src, const int* __restrict__ dst, const int* __restrict__ et,
    const float* __restrict__ Watt, const float* __restrict__ pri,
    float* __restrict__ attb)
{
  int idx = blockIdx.x*256 + threadIdx.x;
  int e = idx >> 2;
  if (e >= NE) return;
  int h = idx & 3;
  int s = src[e], dn = dst[e], r = et[e];
  const float* kr = kbuf + (size_t)s*DD + h*DHH;
  const float* qr = qbuf + (size_t)dn*DD + h*DHH;
  const float* w  = Watt + ((h*RR + r) << 10);
  float qreg[DHH];
  #pragma unroll
  for (int i=0;i<8;i++){
    float4 t4 = ((const float4*)qr)[i];
    qreg[4*i]=t4.x; qreg[4*i+1]=t4.y; qreg[4*i+2]=t4.z; qreg[4*i+3]=t4.w;
  }
  float a = 0.f;
  #pragma unroll 4
  for (int d=0; d<DHH; d++){
    const float4* wr = (const float4*)(w + d*DHH);
    float tmp = 0.f;
    #pragma unroll
    for (int i=0;i<8;i++){
      float4 wv = wr[i];
      tmp += wv.x*qreg[4*i] + wv.y*qreg[4*i+1] + wv.z*qreg[4*i+2] + wv.w*qreg[4*i+3];
    }
    a += kr[d]*tmp;
  }
  a *= pri[h*RR + r] * 0.17677669529663687f;
  attb[e*HH + h] = a;
}

// ---------------- edge softmax over dst (CSR) ----------------
__global__ __launch_bounds__(256) void softmax_kernel(
    const int* __restrict__ rowptr, const int* __restrict__ csr, float* __restrict__ attb)
{
  int idx = blockIdx.x*256 + threadIdx.x;
  int n = idx >> 2;
  if (n >= NN) return;
  int h = idx & 3;
  int b = rowptr[n], eend = rowptr[n+1];
  float m = -1e30f;
  for (int i=b;i<eend;i++){ float a = attb[csr[i]*HH + h]; m = fmaxf(m, a); }
  float den = 0.f;
  for (int i=b;i<eend;i++){
    int ii = csr[i]*HH + h;
    float ex = __expf(attb[ii] - m);
    den += ex;
    attb[ii] = ex;
  }
  float inv = 1.f/den;
  for (int i=b;i<eend;i++){ int ii = csr[i]*HH + h; attb[ii] *= inv; }
}

// ---------------- message + aggregation (CSR, no atomics) ----------------
__global__ __launch_bounds__(128) void agg_kernel(
    const float* __restrict__ vbuf, const float* __restrict__ attb,
    const int* __restrict__ rowptr, const int* __restrict__ csr,
    const int* __restrict__ src, const int* __restrict__ et,
    const float* __restrict__ WmsgT, float* __restrict__ aggout)
{
  int n = blockIdx.x;
  int tid = threadIdx.x;
  int h = tid >> 5, o = tid & 31;
  __shared__ float vrow[DD];
  __shared__ float attsh[HH];
  int b = rowptr[n], eend = rowptr[n+1];
  float acc = 0.f;
  for (int i=b; i<eend; i++){
    int e = csr[i];
    int s = src[e], r = et[e];
    __syncthreads();
    vrow[tid] = vbuf[(size_t)s*DD + tid];
    if (o == 0) attsh[h] = attb[e*HH + h];
    __syncthreads();
    const float4* wr = (const float4*)(WmsgT + ((h*RR + r) << 10) + (o << 5));
    const float4* vr = (const float4*)(vrow + (h << 5));
    float mv = 0.f;
    #pragma unroll
    for (int i4=0;i4<8;i4++){
      float4 wv = wr[i4], vv = vr[i4];
      mv += wv.x*vv.x + wv.y*vv.y + wv.z*vv.z + wv.w*vv.w;
    }
    acc += attsh[h]*mv;
  }
  aggout[(size_t)n*DD + tid] = acc;
}

// ---------------- typed output GEMM + skip gate ----------------
__global__ __launch_bounds__(256) void ha_kernel(
    const float* __restrict__ aggb, const float* __restrict__ x, const int* __restrict__ ntype,
    const float* __restrict__ Wa, const float* __restrict__ skipl, float* __restrict__ ho)
{
  __shared__ float xs[16][DD];
  __shared__ int nts[16];
  int tid = threadIdx.x;
  int n0 = blockIdx.x * 16;
  #pragma unroll
  for (int it=0; it<8; it++){
    int i = tid + it*256;
    xs[i>>7][i&127] = aggb[(size_t)n0*DD + i];
  }
  if (tid < 16) nts[tid] = ntype[n0 + tid];
  __syncthreads();
  int c = tid & 127, nb = (tid >> 7) * 8;
  float acc[8];
  #pragma unroll
  for (int j=0;j<8;j++) acc[j]=0.f;
  int t0 = nts[nb];
  bool uni = true;
  #pragma unroll
  for (int j=1;j<8;j++) uni = uni && (nts[nb+j] == t0);
  if (uni){
    const float* wa = Wa + (size_t)t0*DD*DD + c;
    for (int d=0; d<DD; d+=4){
      float w0=wa[(d+0)*DD], w1=wa[(d+1)*DD], w2=wa[(d+2)*DD], w3=wa[(d+3)*DD];
      #pragma unroll
      for (int j=0;j<8;j++){
        float4 xv = *(const float4*)&xs[nb+j][d];
        acc[j] += xv.x*w0 + xv.y*w1 + xv.z*w2 + xv.w*w3;
      }
    }
  } else {
    #pragma unroll
    for (int j=0;j<8;j++){
      int t = nts[nb+j];
      const float* wa = Wa + (size_t)t*DD*DD + c;
      float sacc = 0.f;
      for (int d=0; d<DD; d+=4){
        float4 xv = *(const float4*)&xs[nb+j][d];
        sacc += xv.x*wa[d*DD] + xv.y*wa[(d+1)*DD] + xv.z*wa[(d+2)*DD] + xv.w*wa[(d+3)*DD];
      }
      acc[j] = sacc;
    }
  }
  #pragma unroll
  for (int j=0;j<8;j++){
    int n = n0 + nb + j;
    float sk = 1.f/(1.f + __expf(-skipl[nts[nb+j]]));
    size_t row = (size_t)n*DD + c;
    ho[row] = acc[j]*sk + x[row]*(1.f - sk);
  }
}

// ---------------- LayerNorm(x + ho) ----------------
__global__ __launch_bounds__(256) void ln_kernel(
    const float* __restrict__ x, const float* __restrict__ ho,
    const float* __restrict__ g, const float* __restrict__ b,
    float* __restrict__ xout)
{
  int lane = threadIdx.x & 63;
  int n = blockIdx.x*4 + (threadIdx.x >> 6);
  size_t base = (size_t)n*DD;
  float t0 = x[base+lane]    + ho[base+lane];
  float t1 = x[base+lane+64] + ho[base+lane+64];
  float s = t0 + t1;
  #pragma unroll
  for (int off=32; off>0; off>>=1) s += __shfl_xor(s, off);
  float mu = s * (1.f/DD);
  float d0 = t0-mu, d1 = t1-mu;
  float vs = d0*d0 + d1*d1;
  #pragma unroll
  for (int off=32; off>0; off>>=1) vs += __shfl_xor(vs, off);
  float inv = rsqrtf(vs*(1.f/DD) + EPSF);
  xout[base+lane]    = d0*inv*g[lane]    + b[lane];
  xout[base+lane+64] = d1*inv*g[lane+64] + b[lane+64];
}

// ---------------- final mix + LayerNorm ----------------
__global__ __launch_bounds__(256) void final_kernel(
    const float* __restrict__ x1, const float* __restrict__ x2,
    const float* __restrict__ aggw, const float* __restrict__ g, const float* __restrict__ b,
    float* __restrict__ out)
{
  int lane = threadIdx.x & 63;
  int n = blockIdx.x*4 + (threadIdx.x >> 6);
  float a0 = aggw[0], a1 = aggw[1];
  float m = fmaxf(a0, a1);
  float e0 = __expf(a0-m), e1 = __expf(a1-m);
  float inv01 = 1.f/(e0+e1);
  float w0 = e0*inv01, w1 = e1*inv01;
  size_t base = (size_t)n*DD;
  float t0 = w0*x1[base+lane]    + w1*x2[base+lane];
  float t1 = w0*x1[base+lane+64] + w1*x2[base+lane+64];
  float s = t0 + t1;
  #pragma unroll
  for (int off=32; off>0; off>>=1) s += __shfl_xor(s, off);
  float mu = s * (1.f/DD);
  float d0 = t0-mu, d1 = t1-mu;
  float vs = d0*d0 + d1*d1;
  #pragma unroll
  for (int off=32; off>0; off>>=1) vs += __shfl_xor(vs, off);
  float invv = rsqrtf(vs*(1.f/DD) + EPSF);
  out[base+lane]    = d0*invv*g[lane]    + b[lane];
  out[base+lane+64] = d1*invv*g[lane+64] + b[lane+64];
}

extern "C" void kernel_launch(void* const* d_in, const int* in_sizes, int n_in,
                              void* d_out, int out_size, void* d_ws, size_t ws_size,
                              hipStream_t stream)
{
  (void)in_sizes; (void)n_in; (void)out_size; (void)ws_size;
  const float* h_in  = (const float*)d_in[0];
  const int*   src   = (const int*)d_in[1];
  const int*   dst   = (const int*)d_in[2];
  const int*   ntype = (const int*)d_in[3];
  const int*   etype = (const int*)d_in[4];
  const float* Wk    = (const float*)d_in[5];
  const float* Wq    = (const float*)d_in[6];
  const float* Wv    = (const float*)d_in[7];
  const float* Wa    = (const float*)d_in[8];
  const float* Watt  = (const float*)d_in[9];
  const float* Wmsg  = (const float*)d_in[10];
  const float* pri   = (const float*)d_in[11];
  const float* skp   = (const float*)d_in[12];
  const float* lng   = (const float*)d_in[13];
  const float* lnb   = (const float*)d_in[14];
  const float* aggw  = (const float*)d_in[15];
  const float* aggg  = (const float*)d_in[16];
  const float* aggb  = (const float*)d_in[17];

  float* fws = (float*)d_ws;
  size_t P = (size_t)NN*DD;
  float* kbuf = fws;               // also agg output
  float* qbuf = kbuf + P;          // also ho output
  float* vbuf = qbuf + P;
  float* out0 = vbuf + P;          // layer-0 output
  float* attb = out0 + P;          // E*H
  float* wT   = attb + (size_t)NE*HH;              // L*H*R*DH*DH
  int* rowptr = (int*)(wT + (size_t)LL*HH*RR*DHH*DHH);
  int* cnt    = rowptr + NN + 1;
  int* csr    = cnt + NN;
  float* xout = (float*)d_out;

  // CSR by dst
  hipMemsetAsync(cnt, 0, NN*sizeof(int), stream);
  hist_kernel<<<(NE+255)/256, 256, 0, stream>>>(dst, cnt);
  scan_kernel<<<1, 1024, 0, stream>>>(cnt, rowptr);
  hipMemsetAsync(cnt, 0, NN*sizeof(int), stream);
  scatter_kernel<<<(NE+255)/256, 256, 0, stream>>>(dst, rowptr, cnt, csr);
  wt_kernel<<<(LL*HH*RR*DHH*DHH+255)/256, 256, 0, stream>>>(Wmsg, wT);

  const float* x = h_in;
  for (int l=0; l<LL; l++){
    const float* Wk_l  = Wk  + (size_t)l*TT*DD*DD;
    const float* Wq_l  = Wq  + (size_t)l*TT*DD*DD;
    const float* Wv_l  = Wv  + (size_t)l*TT*DD*DD;
    const float* Wa_l  = Wa  + (size_t)l*TT*DD*DD;
    const float* Wat_l = Watt + (size_t)l*HH*RR*DHH*DHH;
    const float* wT_l  = wT   + (size_t)l*HH*RR*DHH*DHH;
    const float* pri_l = pri + (size_t)l*HH*RR;
    const float* skp_l = skp + (size_t)l*TT;

    kqv_kernel<<<NN/16, 256, 0, stream>>>(x, ntype, Wk_l, Wq_l, Wv_l, kbuf, qbuf, vbuf);
    logits_kernel<<<(NE*HH)/256, 256, 0, stream>>>(kbuf, qbuf, src, dst, etype, Wat_l, pri_l, attb);
    softmax_kernel<<<(NN*HH+255)/256, 256, 0, stream>>>(rowptr, csr, attb);
    agg_kernel<<<NN, 128, 0, stream>>>(vbuf, attb, rowptr, csr, src, etype, wT_l, kbuf);
    ha_kernel<<<NN/16, 256, 0, stream>>>(kbuf, x, ntype, Wa_l, skp_l, qbuf);
    float* xo = (l == 0) ? out0 : xout;
    ln_kernel<<<NN/4, 256, 0, stream>>>(x, qbuf, lng + (size_t)l*DD, lnb + (size_t)l*DD, xo);
    x = xo;
  }
  final_kernel<<<NN/4, 256, 0, stream>>>(out0, xout, aggw, aggg, aggb, xout);
}

// Round 3
// 2938.723 us; speedup vs baseline: 1.1632x; 1.1632x over previous
//
#include <hip/hip_runtime.h>

#define NN 50000
#define NE 400000
#define DD 128
#define HH 4
#define DHH 32
#define TT 3
#define RR 6
#define LL 2
#define EPSF 1e-5f

typedef unsigned short ushort_t;
typedef unsigned int uint_t;

__device__ inline ushort_t f2bf(float f){
  union { float f; uint_t u; } x; x.f = f;
  uint_t r = x.u + 0x7fffu + ((x.u >> 16) & 1u);
  return (ushort_t)(r >> 16);
}
__device__ inline float bf2f(ushort_t u){
  union { uint_t u; float f; } x; x.u = ((uint_t)u) << 16;
  return x.f;
}

// ---------------- CSR build ----------------
__global__ void hist_kernel(const int* __restrict__ dst, int* __restrict__ cnt){
  int e = blockIdx.x*256 + threadIdx.x;
  if (e < NE) atomicAdd(&cnt[dst[e]], 1);
}

__global__ void scan_kernel(const int* __restrict__ deg, int* __restrict__ rowptr){
  __shared__ int wsum[16];
  __shared__ int carrySh;
  int tid = threadIdx.x, lane = tid & 63, w = tid >> 6;
  if (tid == 0){ carrySh = 0; rowptr[0] = 0; }
  __syncthreads();
  for (int base = 0; base < NN; base += 1024){
    int i = base + tid;
    int v = (i < NN) ? deg[i] : 0;
    int s = v;
    #pragma unroll
    for (int off=1; off<64; off<<=1){ int t = __shfl_up(s, off); if (lane >= off) s += t; }
    if (lane == 63) wsum[w] = s;
    __syncthreads();
    if (w == 0 && lane < 16){
      int t = wsum[lane];
      #pragma unroll
      for (int off=1; off<16; off<<=1){ int u = __shfl_up(t, off); if (lane >= off) t += u; }
      wsum[lane] = t;
    }
    __syncthreads();
    int waveOff = (w == 0) ? 0 : wsum[w-1];
    int incl = s + waveOff + carrySh;
    if (i < NN) rowptr[i+1] = incl;
    __syncthreads();
    if (tid == 0) carrySh += wsum[15];
    __syncthreads();
  }
}

__global__ void scatter_kernel(const int* __restrict__ dst, const int* __restrict__ rowptr,
                               int* __restrict__ cnt, int* __restrict__ csr){
  int e = blockIdx.x*256 + threadIdx.x;
  if (e < NE){
    int d = dst[e];
    int pos = rowptr[d] + atomicAdd(&cnt[d], 1);
    csr[pos] = e;
  }
}

// transpose W_msg[l][h][r][d][o] -> WT[l][h][r][o][d]  (both layers at once)
__global__ void wt_kernel(const float* __restrict__ W, float* __restrict__ WT){
  int i = blockIdx.x*256 + threadIdx.x;
  if (i < LL*HH*RR*DHH*DHH){
    int o = i & 31, d = (i >> 5) & 31, hr = i >> 10;
    WT[(hr << 10) + o*DHH + d] = W[i];
  }
}

// ---------------- typed K/Q/V GEMM (K,V out bf16; Q out fp32) ----------------
__global__ __launch_bounds__(256) void kqv_kernel(
    const float* __restrict__ x, const int* __restrict__ ntype,
    const float* __restrict__ Wk, const float* __restrict__ Wq, const float* __restrict__ Wv,
    ushort_t* __restrict__ kout, float* __restrict__ qout, ushort_t* __restrict__ vout)
{
  __shared__ float xs[16][DD];
  __shared__ int nts[16];
  int tid = threadIdx.x;
  int n0 = blockIdx.x * 16;
  #pragma unroll
  for (int it=0; it<8; it++){
    int i = tid + it*256;
    xs[i>>7][i&127] = x[(size_t)n0*DD + i];
  }
  if (tid < 16) nts[tid] = ntype[n0 + tid];
  __syncthreads();
  int c = tid & 127, nb = (tid >> 7) * 8;
  float ak[8], aq[8], av[8];
  #pragma unroll
  for (int j=0;j<8;j++){ ak[j]=0.f; aq[j]=0.f; av[j]=0.f; }
  int t0 = nts[nb];
  bool uni = true;
  #pragma unroll
  for (int j=1;j<8;j++) uni = uni && (nts[nb+j] == t0);
  if (uni){
    const float* wk = Wk + (size_t)t0*DD*DD + c;
    const float* wq = Wq + (size_t)t0*DD*DD + c;
    const float* wv = Wv + (size_t)t0*DD*DD + c;
    for (int d=0; d<DD; d+=4){
      float k0=wk[(d+0)*DD], k1=wk[(d+1)*DD], k2=wk[(d+2)*DD], k3=wk[(d+3)*DD];
      float q0=wq[(d+0)*DD], q1=wq[(d+1)*DD], q2=wq[(d+2)*DD], q3=wq[(d+3)*DD];
      float v0=wv[(d+0)*DD], v1=wv[(d+1)*DD], v2=wv[(d+2)*DD], v3=wv[(d+3)*DD];
      #pragma unroll
      for (int j=0;j<8;j++){
        float4 xv = *(const float4*)&xs[nb+j][d];
        ak[j] += xv.x*k0 + xv.y*k1 + xv.z*k2 + xv.w*k3;
        aq[j] += xv.x*q0 + xv.y*q1 + xv.z*q2 + xv.w*q3;
        av[j] += xv.x*v0 + xv.y*v1 + xv.z*v2 + xv.w*v3;
      }
    }
  } else {
    #pragma unroll
    for (int j=0;j<8;j++){
      int t = nts[nb+j];
      const float* wk = Wk + (size_t)t*DD*DD + c;
      const float* wq = Wq + (size_t)t*DD*DD + c;
      const float* wv = Wv + (size_t)t*DD*DD + c;
      float sk=0.f, sq=0.f, sv=0.f;
      for (int d=0; d<DD; d+=4){
        float4 xv = *(const float4*)&xs[nb+j][d];
        sk += xv.x*wk[d*DD] + xv.y*wk[(d+1)*DD] + xv.z*wk[(d+2)*DD] + xv.w*wk[(d+3)*DD];
        sq += xv.x*wq[d*DD] + xv.y*wq[(d+1)*DD] + xv.z*wq[(d+2)*DD] + xv.w*wq[(d+3)*DD];
        sv += xv.x*wv[d*DD] + xv.y*wv[(d+1)*DD] + xv.z*wv[(d+2)*DD] + xv.w*wv[(d+3)*DD];
      }
      ak[j]=sk; aq[j]=sq; av[j]=sv;
    }
  }
  #pragma unroll
  for (int j=0;j<8;j++){
    size_t row = (size_t)(n0 + nb + j)*DD + c;
    kout[row]=f2bf(ak[j]); qout[row]=aq[j]; vout[row]=f2bf(av[j]);
  }
}

// ---------------- fused edge pipeline: logits + softmax + aggregation ----------------
// one 128-thread block per destination node; online softmax; no atomics, no attb
// logit: a = sum_d k[d] * qhat[d],  qhat[d] = sum_o Watt[h][r][d][o] * q[o]
__global__ __launch_bounds__(128) void edge_kernel(
    const ushort_t* __restrict__ kb, const float* __restrict__ qb, const ushort_t* __restrict__ vb,
    const int* __restrict__ rowptr, const int* __restrict__ csr,
    const int* __restrict__ src, const int* __restrict__ et,
    const float* __restrict__ Watt, const float* __restrict__ WmsgT, const float* __restrict__ pri,
    float* __restrict__ aggout)
{
  int n = blockIdx.x;
  int tid = threadIdx.x;          // 128 = H*DH
  int h = tid >> 5, o = tid & 31; // o doubles as this thread's d-slot
  __shared__ float qsh[DD];
  __shared__ float qhat[RR][DD];  // qhat[r][h*32+d] = sum_o Watt[h][r][d][o]*q[h*32+o]
  __shared__ float psh[HH*RR];
  qsh[tid] = qb[(size_t)n*DD + tid];
  if (tid < HH*RR) psh[tid] = pri[tid] * 0.17677669529663687f;
  __syncthreads();
  #pragma unroll
  for (int r=0;r<RR;r++){
    // row d = o of Watt[h][r], contiguous over output col
    const float4* w4 = (const float4*)(Watt + (((h*RR + r) << 10) + (o << 5)));
    const float4* q4 = (const float4*)(qsh + (h << 5));
    float s = 0.f;
    #pragma unroll
    for (int i4=0; i4<8; i4++){
      float4 wv = w4[i4], qv = q4[i4];
      s += wv.x*qv.x + wv.y*qv.y + wv.z*qv.z + wv.w*qv.w;
    }
    qhat[r][tid] = s;
  }
  __syncthreads();

  int b = rowptr[n], e1 = rowptr[n+1];
  float mcur = -1e30f, den = 0.f, acc = 0.f;
  int lbase = (h & 1) << 5;   // within-wave lane base holding v[h*32 + ...]
  for (int i=b; i<e1; i++){
    int e = csr[i];
    int s = src[e], r = et[e];
    float kval = bf2f(kb[(size_t)s*DD + tid]);
    float vval = bf2f(vb[(size_t)s*DD + tid]);
    // logit: sum over d (32 lanes of this head-group)
    float p = kval * qhat[r][tid];
    #pragma unroll
    for (int off=16; off>0; off>>=1) p += __shfl_xor(p, off);
    float a = p * psh[h*RR + r];
    // message: mv_o = sum_d WmsgT[h][r][o][d] * v[h*32+d]
    const float* wm = WmsgT + (((h*RR + r) << 10) + (o << 5));
    float mv = 0.f;
    #pragma unroll
    for (int d=0; d<DHH; d++){
      float vd = __shfl(vval, lbase + d);
      mv += wm[d] * vd;
    }
    // online softmax accumulate
    float mnew = fmaxf(mcur, a);
    float corr = __expf(mcur - mnew);
    float ex = __expf(a - mnew);
    den = den*corr + ex;
    acc = acc*corr + ex*mv;
    mcur = mnew;
  }
  float inv = (den > 0.f) ? 1.f/den : 0.f;
  aggout[(size_t)n*DD + tid] = acc * inv;
}

// ---------------- typed output GEMM + skip gate (in-place safe) ----------------
__global__ __launch_bounds__(256) void ha_kernel(
    const float* __restrict__ aggb, const float* __restrict__ x, const int* __restrict__ ntype,
    const float* __restrict__ Wa, const float* __restrict__ skipl, float* __restrict__ ho)
{
  __shared__ float xs[16][DD];
  __shared__ int nts[16];
  int tid = threadIdx.x;
  int n0 = blockIdx.x * 16;
  #pragma unroll
  for (int it=0; it<8; it++){
    int i = tid + it*256;
    xs[i>>7][i&127] = aggb[(size_t)n0*DD + i];
  }
  if (tid < 16) nts[tid] = ntype[n0 + tid];
  __syncthreads();
  int c = tid & 127, nb = (tid >> 7) * 8;
  float acc[8];
  #pragma unroll
  for (int j=0;j<8;j++) acc[j]=0.f;
  int t0 = nts[nb];
  bool uni = true;
  #pragma unroll
  for (int j=1;j<8;j++) uni = uni && (nts[nb+j] == t0);
  if (uni){
    const float* wa = Wa + (size_t)t0*DD*DD + c;
    for (int d=0; d<DD; d+=4){
      float w0=wa[(d+0)*DD], w1=wa[(d+1)*DD], w2=wa[(d+2)*DD], w3=wa[(d+3)*DD];
      #pragma unroll
      for (int j=0;j<8;j++){
        float4 xv = *(const float4*)&xs[nb+j][d];
        acc[j] += xv.x*w0 + xv.y*w1 + xv.z*w2 + xv.w*w3;
      }
    }
  } else {
    #pragma unroll
    for (int j=0;j<8;j++){
      int t = nts[nb+j];
      const float* wa = Wa + (size_t)t*DD*DD + c;
      float sacc = 0.f;
      for (int d=0; d<DD; d+=4){
        float4 xv = *(const float4*)&xs[nb+j][d];
        sacc += xv.x*wa[d*DD] + xv.y*wa[(d+1)*DD] + xv.z*wa[(d+2)*DD] + xv.w*wa[(d+3)*DD];
      }
      acc[j] = sacc;
    }
  }
  #pragma unroll
  for (int j=0;j<8;j++){
    int n = n0 + nb + j;
    float sk = 1.f/(1.f + __expf(-skipl[nts[nb+j]]));
    size_t row = (size_t)n*DD + c;
    ho[row] = acc[j]*sk + x[row]*(1.f - sk);
  }
}

// ---------------- LayerNorm(x + ho) ----------------
__global__ __launch_bounds__(256) void ln_kernel(
    const float* __restrict__ x, const float* __restrict__ ho,
    const float* __restrict__ g, const float* __restrict__ b,
    float* __restrict__ xout)
{
  int lane = threadIdx.x & 63;
  int n = blockIdx.x*4 + (threadIdx.x >> 6);
  size_t base = (size_t)n*DD;
  float t0 = x[base+lane]    + ho[base+lane];
  float t1 = x[base+lane+64] + ho[base+lane+64];
  float s = t0 + t1;
  #pragma unroll
  for (int off=32; off>0; off>>=1) s += __shfl_xor(s, off);
  float mu = s * (1.f/DD);
  float d0 = t0-mu, d1 = t1-mu;
  float vs = d0*d0 + d1*d1;
  #pragma unroll
  for (int off=32; off>0; off>>=1) vs += __shfl_xor(vs, off);
  float inv = rsqrtf(vs*(1.f/DD) + EPSF);
  xout[base+lane]    = d0*inv*g[lane]    + b[lane];
  xout[base+lane+64] = d1*inv*g[lane+64] + b[lane+64];
}

// ---------------- final mix + LayerNorm ----------------
__global__ __launch_bounds__(256) void final_kernel(
    const float* __restrict__ x1, const float* __restrict__ x2,
    const float* __restrict__ aggw, const float* __restrict__ g, const float* __restrict__ b,
    float* __restrict__ out)
{
  int lane = threadIdx.x & 63;
  int n = blockIdx.x*4 + (threadIdx.x >> 6);
  float a0 = aggw[0], a1 = aggw[1];
  float m = fmaxf(a0, a1);
  float e0 = __expf(a0-m), e1 = __expf(a1-m);
  float inv01 = 1.f/(e0+e1);
  float w0 = e0*inv01, w1 = e1*inv01;
  size_t base = (size_t)n*DD;
  float t0 = w0*x1[base+lane]    + w1*x2[base+lane];
  float t1 = w0*x1[base+lane+64] + w1*x2[base+lane+64];
  float s = t0 + t1;
  #pragma unroll
  for (int off=32; off>0; off>>=1) s += __shfl_xor(s, off);
  float mu = s * (1.f/DD);
  float d0 = t0-mu, d1 = t1-mu;
  float vs = d0*d0 + d1*d1;
  #pragma unroll
  for (int off=32; off>0; off>>=1) vs += __shfl_xor(vs, off);
  float invv = rsqrtf(vs*(1.f/DD) + EPSF);
  out[base+lane]    = d0*invv*g[lane]    + b[lane];
  out[base+lane+64] = d1*invv*g[lane+64] + b[lane+64];
}

extern "C" void kernel_launch(void* const* d_in, const int* in_sizes, int n_in,
                              void* d_out, int out_size, void* d_ws, size_t ws_size,
                              hipStream_t stream)
{
  (void)in_sizes; (void)n_in; (void)out_size; (void)ws_size;
  const float* h_in  = (const float*)d_in[0];
  const int*   src   = (const int*)d_in[1];
  const int*   dst   = (const int*)d_in[2];
  const int*   ntype = (const int*)d_in[3];
  const int*   etype = (const int*)d_in[4];
  const float* Wk    = (const float*)d_in[5];
  const float* Wq    = (const float*)d_in[6];
  const float* Wv    = (const float*)d_in[7];
  const float* Wa    = (const float*)d_in[8];
  const float* Watt  = (const float*)d_in[9];
  const float* Wmsg  = (const float*)d_in[10];
  const float* pri   = (const float*)d_in[11];
  const float* skp   = (const float*)d_in[12];
  const float* lng   = (const float*)d_in[13];
  const float* lnb   = (const float*)d_in[14];
  const float* aggw  = (const float*)d_in[15];
  const float* aggg  = (const float*)d_in[16];
  const float* aggb_ = (const float*)d_in[17];

  size_t P = (size_t)NN*DD;
  ushort_t* kb16 = (ushort_t*)d_ws;              // P bf16
  ushort_t* vb16 = kb16 + P;                     // P bf16
  float* qbuf = (float*)(vb16 + P);              // P f32
  float* aggb = qbuf + P;                        // P f32 (agg, then ho in-place)
  float* out0 = aggb + P;                        // P f32 (layer-0 output)
  float* wT   = out0 + P;                        // L*H*R*DH*DH
  int* rowptr = (int*)(wT + (size_t)LL*HH*RR*DHH*DHH);
  int* cnt    = rowptr + NN + 1;
  int* csr    = cnt + NN;
  float* xout = (float*)d_out;

  // CSR by dst
  hipMemsetAsync(cnt, 0, NN*sizeof(int), stream);
  hist_kernel<<<(NE+255)/256, 256, 0, stream>>>(dst, cnt);
  scan_kernel<<<1, 1024, 0, stream>>>(cnt, rowptr);
  hipMemsetAsync(cnt, 0, NN*sizeof(int), stream);
  scatter_kernel<<<(NE+255)/256, 256, 0, stream>>>(dst, rowptr, cnt, csr);
  wt_kernel<<<(LL*HH*RR*DHH*DHH+255)/256, 256, 0, stream>>>(Wmsg, wT);

  const float* x = h_in;
  for (int l=0; l<LL; l++){
    const float* Wk_l  = Wk  + (size_t)l*TT*DD*DD;
    const float* Wq_l  = Wq  + (size_t)l*TT*DD*DD;
    const float* Wv_l  = Wv  + (size_t)l*TT*DD*DD;
    const float* Wa_l  = Wa  + (size_t)l*TT*DD*DD;
    const float* Wat_l = Watt + (size_t)l*HH*RR*DHH*DHH;
    const float* wT_l  = wT   + (size_t)l*HH*RR*DHH*DHH;
    const float* pri_l = pri + (size_t)l*HH*RR;
    const float* skp_l = skp + (size_t)l*TT;

    kqv_kernel<<<NN/16, 256, 0, stream>>>(x, ntype, Wk_l, Wq_l, Wv_l, kb16, qbuf, vb16);
    edge_kernel<<<NN, 128, 0, stream>>>(kb16, qbuf, vb16, rowptr, csr, src, etype,
                                        Wat_l, wT_l, pri_l, aggb);
    ha_kernel<<<NN/16, 256, 0, stream>>>(aggb, x, ntype, Wa_l, skp_l, aggb);
    float* xo = (l == 0) ? out0 : xout;
    ln_kernel<<<NN/4, 256, 0, stream>>>(x, aggb, lng + (size_t)l*DD, lnb + (size_t)l*DD, xo);
    x = xo;
  }
  final_kernel<<<NN/4, 256, 0, stream>>>(out0, xout, aggw, aggg, aggb_, xout);
}

// Round 4
// 1847.977 us; speedup vs baseline: 1.8498x; 1.5902x over previous
//
#include <hip/hip_runtime.h>

#define NN 50000
#define NE 400000
#define DD 128
#define HH 4
#define DHH 32
#define TT 3
#define RR 6
#define LL 2
#define EPSF 1e-5f

typedef unsigned short ushort_t;
typedef unsigned int uint_t;

__device__ inline ushort_t f2bf(float f){
  union { float f; uint_t u; } x; x.f = f;
  uint_t r = x.u + 0x7fffu + ((x.u >> 16) & 1u);
  return (ushort_t)(r >> 16);
}
__device__ inline float bf2f(ushort_t u){
  union { uint_t u; float f; } x; x.u = ((uint_t)u) << 16;
  return x.f;
}

// ---------------- CSR build ----------------
__global__ void hist_kernel(const int* __restrict__ dst, int* __restrict__ cnt){
  int e = blockIdx.x*256 + threadIdx.x;
  if (e < NE) atomicAdd(&cnt[dst[e]], 1);
}

__global__ void scan_kernel(const int* __restrict__ deg, int* __restrict__ rowptr){
  __shared__ int wsum[16];
  __shared__ int carrySh;
  int tid = threadIdx.x, lane = tid & 63, w = tid >> 6;
  if (tid == 0){ carrySh = 0; rowptr[0] = 0; }
  __syncthreads();
  for (int base = 0; base < NN; base += 1024){
    int i = base + tid;
    int v = (i < NN) ? deg[i] : 0;
    int s = v;
    #pragma unroll
    for (int off=1; off<64; off<<=1){ int t = __shfl_up(s, off); if (lane >= off) s += t; }
    if (lane == 63) wsum[w] = s;
    __syncthreads();
    if (w == 0 && lane < 16){
      int t = wsum[lane];
      #pragma unroll
      for (int off=1; off<16; off<<=1){ int u = __shfl_up(t, off); if (lane >= off) t += u; }
      wsum[lane] = t;
    }
    __syncthreads();
    int waveOff = (w == 0) ? 0 : wsum[w-1];
    int incl = s + waveOff + carrySh;
    if (i < NN) rowptr[i+1] = incl;
    __syncthreads();
    if (tid == 0) carrySh += wsum[15];
    __syncthreads();
  }
}

// scatter: write packed (src | etype<<27) in CSR order — kills the per-edge load chain
__global__ void scatter_kernel(const int* __restrict__ dst, const int* __restrict__ src,
                               const int* __restrict__ etype, const int* __restrict__ rowptr,
                               int* __restrict__ cnt, uint_t* __restrict__ sr){
  int e = blockIdx.x*256 + threadIdx.x;
  if (e < NE){
    int d = dst[e];
    int pos = rowptr[d] + atomicAdd(&cnt[d], 1);
    sr[pos] = (uint_t)src[e] | ((uint_t)etype[e] << 27);
  }
}

// ---------------- typed K/Q/V GEMM (K,V packed bf16 pair; Q fp32) ----------------
__global__ __launch_bounds__(256) void kqv_kernel(
    const float* __restrict__ x, const int* __restrict__ ntype,
    const float* __restrict__ Wk, const float* __restrict__ Wq, const float* __restrict__ Wv,
    uint_t* __restrict__ kvout, float* __restrict__ qout)
{
  __shared__ float xs[16][DD];
  __shared__ int nts[16];
  int tid = threadIdx.x;
  int n0 = blockIdx.x * 16;
  #pragma unroll
  for (int it=0; it<8; it++){
    int i = tid + it*256;
    xs[i>>7][i&127] = x[(size_t)n0*DD + i];
  }
  if (tid < 16) nts[tid] = ntype[n0 + tid];
  __syncthreads();
  int c = tid & 127, nb = (tid >> 7) * 8;
  float ak[8], aq[8], av[8];
  #pragma unroll
  for (int j=0;j<8;j++){ ak[j]=0.f; aq[j]=0.f; av[j]=0.f; }
  int t0 = nts[nb];
  bool uni = true;
  #pragma unroll
  for (int j=1;j<8;j++) uni = uni && (nts[nb+j] == t0);
  if (uni){
    const float* wk = Wk + (size_t)t0*DD*DD + c;
    const float* wq = Wq + (size_t)t0*DD*DD + c;
    const float* wv = Wv + (size_t)t0*DD*DD + c;
    for (int d=0; d<DD; d+=4){
      float k0=wk[(d+0)*DD], k1=wk[(d+1)*DD], k2=wk[(d+2)*DD], k3=wk[(d+3)*DD];
      float q0=wq[(d+0)*DD], q1=wq[(d+1)*DD], q2=wq[(d+2)*DD], q3=wq[(d+3)*DD];
      float v0=wv[(d+0)*DD], v1=wv[(d+1)*DD], v2=wv[(d+2)*DD], v3=wv[(d+3)*DD];
      #pragma unroll
      for (int j=0;j<8;j++){
        float4 xv = *(const float4*)&xs[nb+j][d];
        ak[j] += xv.x*k0 + xv.y*k1 + xv.z*k2 + xv.w*k3;
        aq[j] += xv.x*q0 + xv.y*q1 + xv.z*q2 + xv.w*q3;
        av[j] += xv.x*v0 + xv.y*v1 + xv.z*v2 + xv.w*v3;
      }
    }
  } else {
    #pragma unroll
    for (int j=0;j<8;j++){
      int t = nts[nb+j];
      const float* wk = Wk + (size_t)t*DD*DD + c;
      const float* wq = Wq + (size_t)t*DD*DD + c;
      const float* wv = Wv + (size_t)t*DD*DD + c;
      float sk=0.f, sq=0.f, sv=0.f;
      for (int d=0; d<DD; d+=4){
        float4 xv = *(const float4*)&xs[nb+j][d];
        sk += xv.x*wk[d*DD] + xv.y*wk[(d+1)*DD] + xv.z*wk[(d+2)*DD] + xv.w*wk[(d+3)*DD];
        sq += xv.x*wq[d*DD] + xv.y*wq[(d+1)*DD] + xv.z*wq[(d+2)*DD] + xv.w*wq[(d+3)*DD];
        sv += xv.x*wv[d*DD] + xv.y*wv[(d+1)*DD] + xv.z*wv[(d+2)*DD] + xv.w*wv[(d+3)*DD];
      }
      ak[j]=sk; aq[j]=sq; av[j]=sv;
    }
  }
  #pragma unroll
  for (int j=0;j<8;j++){
    size_t row = (size_t)(n0 + nb + j)*DD + c;
    kvout[row] = (uint_t)f2bf(ak[j]) | ((uint_t)f2bf(av[j]) << 16);
    qout[row]  = aq[j];
  }
}

// ---------------- fused edge pipeline ----------------
// one 128-thread block per destination node; online softmax; per-relation
// v-space accumulators (W_msg applied once per node, not per edge);
// 8-wide batched loads of packed (src|etype) + packed (k|v).
__global__ __launch_bounds__(128) void edge_kernel(
    const uint_t* __restrict__ kvb, const float* __restrict__ qb,
    const int* __restrict__ rowptr, const uint_t* __restrict__ src_r,
    const float* __restrict__ Watt, const float* __restrict__ Wmsg, const float* __restrict__ pri,
    float* __restrict__ aggout)
{
  int n = blockIdx.x;
  int tid = threadIdx.x;          // 128 = H*DH
  int h = tid >> 5, o = tid & 31; // o = this thread's d-slot (and output col at the end)
  __shared__ float qsh[DD];
  __shared__ float qhat[RR][DD];  // qhat[r][h*32+d] = sum_c Watt[h][r][d][c]*q[h*32+c]
  __shared__ float sacc[RR][DD];
  __shared__ float psh[HH*RR];
  qsh[tid] = qb[(size_t)n*DD + tid];
  if (tid < HH*RR) psh[tid] = pri[tid] * 0.17677669529663687f;
  __syncthreads();
  #pragma unroll
  for (int r=0;r<RR;r++){
    const float4* w4 = (const float4*)(Watt + (((h*RR + r) << 10) + (o << 5)));
    const float4* q4 = (const float4*)(qsh + (h << 5));
    float s = 0.f;
    #pragma unroll
    for (int i4=0; i4<8; i4++){
      float4 wv = w4[i4], qv = q4[i4];
      s += wv.x*qv.x + wv.y*qv.y + wv.z*qv.z + wv.w*qv.w;
    }
    qhat[r][tid] = s;
  }
  __syncthreads();

  int b = rowptr[n], e1 = rowptr[n+1];
  float a0=0.f,a1=0.f,a2=0.f,a3=0.f,a4=0.f,a5=0.f;
  float den = 0.f, m = -1e30f;
  for (int i=b; i<e1; i+=8){
    int m8 = e1 - i; if (m8 > 8) m8 = 8;
    uint_t sr[8]; uint_t kv[8];
    #pragma unroll
    for (int jj=0;jj<8;jj++){
      int j = (jj < m8) ? jj : (m8-1);
      sr[jj] = src_r[i + j];
    }
    #pragma unroll
    for (int jj=0;jj<8;jj++){
      kv[jj] = kvb[(size_t)(sr[jj] & 0x07FFFFFFu)*DD + tid];
    }
    #pragma unroll
    for (int jj=0;jj<8;jj++){
      if (jj < m8){
        int r = (int)(sr[jj] >> 27);
        float kf = bf2f((ushort_t)(kv[jj] & 0xffffu));
        float vf = bf2f((ushort_t)(kv[jj] >> 16));
        float p = kf * qhat[r][tid];
        #pragma unroll
        for (int off=16; off>0; off>>=1) p += __shfl_xor(p, off);
        float a = p * psh[h*RR + r];
        float mnew = fmaxf(m, a);
        float corr = __expf(m - mnew);
        float ex = __expf(a - mnew);
        den = den*corr + ex;
        m = mnew;
        float exv = ex * vf;
        a0 = a0*corr + ((r==0)? exv : 0.f);
        a1 = a1*corr + ((r==1)? exv : 0.f);
        a2 = a2*corr + ((r==2)? exv : 0.f);
        a3 = a3*corr + ((r==3)? exv : 0.f);
        a4 = a4*corr + ((r==4)? exv : 0.f);
        a5 = a5*corr + ((r==5)? exv : 0.f);
      }
    }
  }
  sacc[0][tid]=a0; sacc[1][tid]=a1; sacc[2][tid]=a2;
  sacc[3][tid]=a3; sacc[4][tid]=a4; sacc[5][tid]=a5;
  __syncthreads();
  // out[o] = (1/den) * sum_r sum_d Wmsg[h][r][d][o] * sacc[r][h*32+d]
  float inv = (den > 0.f) ? 1.f/den : 0.f;
  float sum = 0.f;
  #pragma unroll
  for (int r=0;r<RR;r++){
    const float* wm = Wmsg + ((h*RR + r) << 10) + o;   // [d][o], coalesced over o
    const float* sa = &sacc[r][h << 5];                // LDS broadcast over d
    #pragma unroll
    for (int d=0; d<DHH; d++){
      sum += sa[d] * wm[d << 5];
    }
  }
  aggout[(size_t)n*DD + tid] = sum * inv;
}

// ---------------- typed output GEMM + skip gate (in-place safe) ----------------
__global__ __launch_bounds__(256) void ha_kernel(
    const float* __restrict__ aggb, const float* __restrict__ x, const int* __restrict__ ntype,
    const float* __restrict__ Wa, const float* __restrict__ skipl, float* __restrict__ ho)
{
  __shared__ float xs[16][DD];
  __shared__ int nts[16];
  int tid = threadIdx.x;
  int n0 = blockIdx.x * 16;
  #pragma unroll
  for (int it=0; it<8; it++){
    int i = tid + it*256;
    xs[i>>7][i&127] = aggb[(size_t)n0*DD + i];
  }
  if (tid < 16) nts[tid] = ntype[n0 + tid];
  __syncthreads();
  int c = tid & 127, nb = (tid >> 7) * 8;
  float acc[8];
  #pragma unroll
  for (int j=0;j<8;j++) acc[j]=0.f;
  int t0 = nts[nb];
  bool uni = true;
  #pragma unroll
  for (int j=1;j<8;j++) uni = uni && (nts[nb+j] == t0);
  if (uni){
    const float* wa = Wa + (size_t)t0*DD*DD + c;
    for (int d=0; d<DD; d+=4){
      float w0=wa[(d+0)*DD], w1=wa[(d+1)*DD], w2=wa[(d+2)*DD], w3=wa[(d+3)*DD];
      #pragma unroll
      for (int j=0;j<8;j++){
        float4 xv = *(const float4*)&xs[nb+j][d];
        acc[j] += xv.x*w0 + xv.y*w1 + xv.z*w2 + xv.w*w3;
      }
    }
  } else {
    #pragma unroll
    for (int j=0;j<8;j++){
      int t = nts[nb+j];
      const float* wa = Wa + (size_t)t*DD*DD + c;
      float sacc = 0.f;
      for (int d=0; d<DD; d+=4){
        float4 xv = *(const float4*)&xs[nb+j][d];
        sacc += xv.x*wa[d*DD] + xv.y*wa[(d+1)*DD] + xv.z*wa[(d+2)*DD] + xv.w*wa[(d+3)*DD];
      }
      acc[j] = sacc;
    }
  }
  #pragma unroll
  for (int j=0;j<8;j++){
    int n = n0 + nb + j;
    float sk = 1.f/(1.f + __expf(-skipl[nts[nb+j]]));
    size_t row = (size_t)n*DD + c;
    ho[row] = acc[j]*sk + x[row]*(1.f - sk);
  }
}

// ---------------- LayerNorm(x + ho) ----------------
__global__ __launch_bounds__(256) void ln_kernel(
    const float* __restrict__ x, const float* __restrict__ ho,
    const float* __restrict__ g, const float* __restrict__ b,
    float* __restrict__ xout)
{
  int lane = threadIdx.x & 63;
  int n = blockIdx.x*4 + (threadIdx.x >> 6);
  size_t base = (size_t)n*DD;
  float t0 = x[base+lane]    + ho[base+lane];
  float t1 = x[base+lane+64] + ho[base+lane+64];
  float s = t0 + t1;
  #pragma unroll
  for (int off=32; off>0; off>>=1) s += __shfl_xor(s, off);
  float mu = s * (1.f/DD);
  float d0 = t0-mu, d1 = t1-mu;
  float vs = d0*d0 + d1*d1;
  #pragma unroll
  for (int off=32; off>0; off>>=1) vs += __shfl_xor(vs, off);
  float inv = rsqrtf(vs*(1.f/DD) + EPSF);
  xout[base+lane]    = d0*inv*g[lane]    + b[lane];
  xout[base+lane+64] = d1*inv*g[lane+64] + b[lane+64];
}

// ---------------- final mix + LayerNorm ----------------
__global__ __launch_bounds__(256) void final_kernel(
    const float* __restrict__ x1, const float* __restrict__ x2,
    const float* __restrict__ aggw, const float* __restrict__ g, const float* __restrict__ b,
    float* __restrict__ out)
{
  int lane = threadIdx.x & 63;
  int n = blockIdx.x*4 + (threadIdx.x >> 6);
  float a0 = aggw[0], a1 = aggw[1];
  float m = fmaxf(a0, a1);
  float e0 = __expf(a0-m), e1 = __expf(a1-m);
  float inv01 = 1.f/(e0+e1);
  float w0 = e0*inv01, w1 = e1*inv01;
  size_t base = (size_t)n*DD;
  float t0 = w0*x1[base+lane]    + w1*x2[base+lane];
  float t1 = w0*x1[base+lane+64] + w1*x2[base+lane+64];
  float s = t0 + t1;
  #pragma unroll
  for (int off=32; off>0; off>>=1) s += __shfl_xor(s, off);
  float mu = s * (1.f/DD);
  float d0 = t0-mu, d1 = t1-mu;
  float vs = d0*d0 + d1*d1;
  #pragma unroll
  for (int off=32; off>0; off>>=1) vs += __shfl_xor(vs, off);
  float invv = rsqrtf(vs*(1.f/DD) + EPSF);
  out[base+lane]    = d0*invv*g[lane]    + b[lane];
  out[base+lane+64] = d1*invv*g[lane+64] + b[lane+64];
}

extern "C" void kernel_launch(void* const* d_in, const int* in_sizes, int n_in,
                              void* d_out, int out_size, void* d_ws, size_t ws_size,
                              hipStream_t stream)
{
  (void)in_sizes; (void)n_in; (void)out_size; (void)ws_size;
  const float* h_in  = (const float*)d_in[0];
  const int*   src   = (const int*)d_in[1];
  const int*   dst   = (const int*)d_in[2];
  const int*   ntype = (const int*)d_in[3];
  const int*   etype = (const int*)d_in[4];
  const float* Wk    = (const float*)d_in[5];
  const float* Wq    = (const float*)d_in[6];
  const float* Wv    = (const float*)d_in[7];
  const float* Wa    = (const float*)d_in[8];
  const float* Watt  = (const float*)d_in[9];
  const float* Wmsg  = (const float*)d_in[10];
  const float* pri   = (const float*)d_in[11];
  const float* skp   = (const float*)d_in[12];
  const float* lng   = (const float*)d_in[13];
  const float* lnb   = (const float*)d_in[14];
  const float* aggw  = (const float*)d_in[15];
  const float* aggg  = (const float*)d_in[16];
  const float* aggb_ = (const float*)d_in[17];

  size_t P = (size_t)NN*DD;
  uint_t* kvbuf = (uint_t*)d_ws;                 // P packed (k,v) bf16
  float* qbuf = (float*)(kvbuf + P);             // P f32
  float* aggb = qbuf + P;                        // P f32 (agg, then ho in-place)
  float* out0 = aggb + P;                        // P f32 (layer-0 output)
  int* rowptr = (int*)(out0 + P);
  int* cnt    = rowptr + NN + 1;
  uint_t* srcr = (uint_t*)(cnt + NN);            // NE packed (src | etype<<27)
  float* xout = (float*)d_out;

  // CSR by dst
  hipMemsetAsync(cnt, 0, NN*sizeof(int), stream);
  hist_kernel<<<(NE+255)/256, 256, 0, stream>>>(dst, cnt);
  scan_kernel<<<1, 1024, 0, stream>>>(cnt, rowptr);
  hipMemsetAsync(cnt, 0, NN*sizeof(int), stream);
  scatter_kernel<<<(NE+255)/256, 256, 0, stream>>>(dst, src, etype, rowptr, cnt, srcr);

  const float* x = h_in;
  for (int l=0; l<LL; l++){
    const float* Wk_l  = Wk  + (size_t)l*TT*DD*DD;
    const float* Wq_l  = Wq  + (size_t)l*TT*DD*DD;
    const float* Wv_l  = Wv  + (size_t)l*TT*DD*DD;
    const float* Wa_l  = Wa  + (size_t)l*TT*DD*DD;
    const float* Wat_l = Watt + (size_t)l*HH*RR*DHH*DHH;
    const float* Wms_l = Wmsg + (size_t)l*HH*RR*DHH*DHH;
    const float* pri_l = pri + (size_t)l*HH*RR;
    const float* skp_l = skp + (size_t)l*TT;

    kqv_kernel<<<NN/16, 256, 0, stream>>>(x, ntype, Wk_l, Wq_l, Wv_l, kvbuf, qbuf);
    edge_kernel<<<NN, 128, 0, stream>>>(kvbuf, qbuf, rowptr, srcr,
                                        Wat_l, Wms_l, pri_l, aggb);
    ha_kernel<<<NN/16, 256, 0, stream>>>(aggb, x, ntype, Wa_l, skp_l, aggb);
    float* xo = (l == 0) ? out0 : xout;
    ln_kernel<<<NN/4, 256, 0, stream>>>(x, aggb, lng + (size_t)l*DD, lnb + (size_t)l*DD, xo);
    x = xo;
  }
  final_kernel<<<NN/4, 256, 0, stream>>>(out0, xout, aggw, aggg, aggb_, xout);
}